// Round 10
// baseline (82.367 us; speedup 1.0000x reference)
//
#include <hip/hip_runtime.h>
#include <hip/hip_bf16.h>
#include <math.h>

#define BB 128
#define HH 128
#define WW 512
#define HW (HH*WW)            // 65536 pixels per sample
#define NPIX ((size_t)BB*HW)  // 8388608
#define ROWS 4096
#define COLS 10000
#define P1_BLOCKS (BB*16)     // 2048 image blocks
#define LCE_BLOCKS 4096       // 4 waves/block, 1 wave per QUARTER row (16384 units)
#define GRID (P1_BLOCKS + LCE_BLOCKS)   // 6144

// d_ws layout (every slot written every launch; no zeroing needed):
//   [0,8192)         float l2p[2048]     per-block l2 partials
//   [8192,16384)     int gso[2048]       per-block gray sums (out)
//   [16384,24576)    int gst[2048]       per-block gray sums (tgt)
//   [24576,32768)    float lgp[2048]     per-block lg partials
//   [32768,98304)    float cesp[16384]   per-quarter-row exp sums
//   [98304,114688)   float xgp[4096]     per-row target logit
//   [131072, ...)    u8 gray_out[NPIX], u8 gray_tgt[NPIX]

typedef float vf4 __attribute__((ext_vector_type(4)));

__device__ __forceinline__ int gray_of(float r, float g, float b) {
    int ri = (int)floorf(r * 255.0f);
    int gi = (int)floorf(g * 255.0f);
    int bi = (int)floorf(b * 255.0f);
    return (299 * ri + 587 * gi + 114 * bi) / 1000;
}

__device__ __forceinline__ float e4v(vf4 x) {
    return (__expf(x.x) + __expf(x.y)) + (__expf(x.z) + __expf(x.w));
}

// ---- K1: fused pass1 (outI cached / tgtI non-temporal) + lce (NT) --------
template <bool STORE_GRAY>
__global__ __launch_bounds__(256) void fused1_kernel(
    const float* __restrict__ outI, const float* __restrict__ tgtI,
    const float* __restrict__ X, const int* __restrict__ gt,
    float* __restrict__ l2p, int* __restrict__ gso, int* __restrict__ gst,
    float* __restrict__ cesp, float* __restrict__ xgp,
    unsigned char* __restrict__ gout, unsigned char* __restrict__ gtgt) {
    const int tid = threadIdx.x;
    const int bid = blockIdx.x;
    const int w = tid >> 6, lane = tid & 63;

    if (bid % 3 == 0) {
        // ---------------- pass1: image MSE + gray ----------------
        // outI: normal loads -> stays L3-resident across graph replays.
        // tgtI: non-temporal  -> streams from HBM, doesn't churn L3.
        const int p1    = bid / 3;           // 0..2047
        const int b     = p1 >> 4;
        const int chunk = p1 & 15;           // 4096 px per block
        const float4* o4 = (const float4*)(outI + (size_t)b * 3 * HW) + chunk * 1024;
        const vf4*    t4 = (const vf4*)(tgtI + (size_t)b * 3 * HW) + chunk * 1024;
        uchar4* go4 = (uchar4*)(gout + (size_t)b * HW) + chunk * 1024;
        uchar4* gt4 = (uchar4*)(gtgt + (size_t)b * HW) + chunk * 1024;

        float l2 = 0.0f;
        int so = 0, st = 0;
#pragma unroll
        for (int k = 0; k < 4; ++k) {
            int v = tid + k * 256;
            float4 oR = o4[v], oG = o4[v + HW/4], oB = o4[v + 2*(HW/4)];
            vf4 tR = __builtin_nontemporal_load(t4 + v);
            vf4 tG = __builtin_nontemporal_load(t4 + v + HW/4);
            vf4 tB = __builtin_nontemporal_load(t4 + v + 2*(HW/4));
            float d;
            d = oR.x-tR.x; l2 += d*d;  d = oR.y-tR.y; l2 += d*d;
            d = oR.z-tR.z; l2 += d*d;  d = oR.w-tR.w; l2 += d*d;
            d = oG.x-tG.x; l2 += d*d;  d = oG.y-tG.y; l2 += d*d;
            d = oG.z-tG.z; l2 += d*d;  d = oG.w-tG.w; l2 += d*d;
            d = oB.x-tB.x; l2 += d*d;  d = oB.y-tB.y; l2 += d*d;
            d = oB.z-tB.z; l2 += d*d;  d = oB.w-tB.w; l2 += d*d;

            int g0 = gray_of(oR.x, oG.x, oB.x);
            int g1 = gray_of(oR.y, oG.y, oB.y);
            int g2 = gray_of(oR.z, oG.z, oB.z);
            int g3 = gray_of(oR.w, oG.w, oB.w);
            so += g0 + g1 + g2 + g3;
            if (STORE_GRAY) go4[v] = make_uchar4((unsigned char)g0,(unsigned char)g1,(unsigned char)g2,(unsigned char)g3);
            g0 = gray_of(tR.x, tG.x, tB.x);
            g1 = gray_of(tR.y, tG.y, tB.y);
            g2 = gray_of(tR.z, tG.z, tB.z);
            g3 = gray_of(tR.w, tG.w, tB.w);
            st += g0 + g1 + g2 + g3;
            if (STORE_GRAY) gt4[v] = make_uchar4((unsigned char)g0,(unsigned char)g1,(unsigned char)g2,(unsigned char)g3);
        }

        for (int off = 32; off > 0; off >>= 1) {
            l2 += __shfl_down(l2, off);
            so += __shfl_down(so, off);
            st += __shfl_down(st, off);
        }
        __shared__ float wl2[4];
        __shared__ int w1[4], w2[4];
        if (lane == 0) { wl2[w] = l2; w1[w] = so; w2[w] = st; }
        __syncthreads();
        if (tid == 0) {
            l2p[p1] = wl2[0] + wl2[1] + wl2[2] + wl2[3];
            gso[p1] = w1[0] + w1[1] + w1[2] + w1[3];
            gst[p1] = w2[0] + w2[1] + w2[2] + w2[3];
        }
    } else {
        // ------- lce: one wave per QUARTER row (2500 floats), NT loads ------
        const int lceb = (bid / 3) * 2 + (bid % 3 - 1);   // 0..4095
        const int unit = lceb * 4 + w;                    // 0..16383
        const int row  = unit >> 2;
        const int q    = unit & 3;
        const int g    = (q == 0 && lane == 0) ? gt[row] : 0;   // early gather idx
        const vf4* xq4 = (const vf4*)(X + (size_t)row * COLS + q * 2500);

        float s = 0.0f;
#pragma unroll
        for (int k = 0; k < 9; ++k) {          // float4 idx 0..575
            vf4 a = __builtin_nontemporal_load(xq4 + lane + k * 64);
            s += e4v(a);
        }
        if (lane < 49) {                       // tail: idx 576..624
            vf4 a = __builtin_nontemporal_load(xq4 + 576 + lane);
            s += e4v(a);
        }
        for (int off = 32; off > 0; off >>= 1) s += __shfl_down(s, off);
        if (lane == 0) {
            cesp[unit] = s;
            if (q == 0) xgp[row] = X[(size_t)row * COLS + g];
        }
    }
}

// ---- K2 (cached gray): bit-packed mask gradient --------------------------
__device__ __forceinline__ int mask8(uint2 v, int ti) {
    int m = 0;
#pragma unroll
    for (int k = 0; k < 4; ++k) m |= (((int)((v.x >> (8*k)) & 255) <= ti) ? 1 : 0) << k;
#pragma unroll
    for (int k = 0; k < 4; ++k) m |= (((int)((v.y >> (8*k)) & 255) <= ti) ? 1 : 0) << (k+4);
    return m;
}

__device__ __forceinline__ void grad_bits(const unsigned char* __restrict__ G,
                                          int r, int roff, int ti, int lane,
                                          int& ax, int& vy) {
    uint2 cc = *(const uint2*)(G + roff);
    uint2 aa = *(const uint2*)(G + (r > 0   ? roff - 512 : roff));
    uint2 bb = *(const uint2*)(G + (r < 127 ? roff + 512 : roff));
    int mc = mask8(cc, ti);
    int ma = (r > 0)   ? mask8(aa, ti) : 0;
    int mb = (r < 127) ? mask8(bb, ti) : 0;
    int prev = __shfl_up(mc, 1);
    int next = __shfl_down(mc, 1);
    int lb = ((mc << 1) & 0xFF) | ((lane > 0)  ? ((prev >> 7) & 1) : 0);
    int rb = (mc >> 1)          | ((lane < 63) ? ((next & 1) << 7) : 0);
    ax = lb ^ rb;
    vy = ma ^ mb;
}

__global__ __launch_bounds__(256) void pass2_kernel(
    const unsigned char* __restrict__ gout, const unsigned char* __restrict__ gtgt,
    const int* __restrict__ gso, const int* __restrict__ gst,
    float* __restrict__ lgp) {
    const int tid  = threadIdx.x;
    const int wave = tid >> 6, lane = tid & 63;
    const int b  = blockIdx.x >> 4;   // 16 blocks per sample
    const int rg = blockIdx.x & 15;   // 8 rows per block (4 waves x 2 rows)

    int s_o = 0, s_t = 0;
#pragma unroll
    for (int k = 0; k < 16; ++k) { s_o += gso[b*16 + k]; s_t += gst[b*16 + k]; }
    const int ti_o = s_o >> 16;       // floor(sum/65536): exact threshold
    const int ti_t = s_t >> 16;
    const unsigned char* Go = gout + (size_t)b * HW;
    const unsigned char* Gt = gtgt + (size_t)b * HW;

    const float v0 = sqrtf(1e-6f);
    const float v1 = sqrtf(0.25f + 1e-6f);
    const float v2 = sqrtf(0.5f + 1e-6f);

    float sum = 0.0f;
#pragma unroll
    for (int rr = 0; rr < 2; ++rr) {
        const int r = rg * 8 + wave * 2 + rr;
        const int roff = r * 512 + lane * 8;
        int ax_o, vy_o, ax_t, vy_t;
        grad_bits(Go, r, roff, ti_o, lane, ax_o, vy_o);
        grad_bits(Gt, r, roff, ti_t, lane, ax_t, vy_t);
#pragma unroll
        for (int k = 0; k < 8; ++k) {
            int so = ((ax_o >> k) & 1) + ((vy_o >> k) & 1);
            int st = ((ax_t >> k) & 1) + ((vy_t >> k) & 1);
            float g_o = (so == 0) ? v0 : ((so == 1) ? v1 : v2);
            float g_t = (st == 0) ? v0 : ((st == 1) ? v1 : v2);
            sum += fabsf(g_o - g_t);
        }
    }

    for (int off = 32; off > 0; off >>= 1) sum += __shfl_down(sum, off);
    __shared__ float ws4[4];
    if (lane == 0) ws4[wave] = sum;
    __syncthreads();
    if (tid == 0) lgp[blockIdx.x] = ws4[0] + ws4[1] + ws4[2] + ws4[3];
}

// ---- K2 fallback (no gray cache): recompute gray from images -------------
__device__ __forceinline__ float mask_at(const float* __restrict__ img, size_t base, int p, float thres) {
    float r = img[base + p], g = img[base + p + HW], b = img[base + p + 2*HW];
    return ((float)gray_of(r, g, b) > thres) ? 0.0f : 1.0f;
}

__global__ __launch_bounds__(256) void pass2_recompute_kernel(
    const float* __restrict__ outI, const float* __restrict__ tgtI,
    const int* __restrict__ gso, const int* __restrict__ gst,
    float* __restrict__ lgp) {
    const int tid   = threadIdx.x;
    const int b     = blockIdx.x >> 4;
    const int chunk = blockIdx.x & 15;
    int s_o = 0, s_t = 0;
    for (int k = 0; k < 16; ++k) { s_o += gso[b*16 + k]; s_t += gst[b*16 + k]; }
    const float to = (float)s_o * (1.0f/65536.0f);
    const float tt = (float)s_t * (1.0f/65536.0f);
    const size_t baseO = (size_t)b * 3 * HW;

    float sum = 0.0f;
    for (int u = 0; u < 16; ++u) {
        int p = chunk * 4096 + u * 256 + tid;
        int i = p >> 9, j = p & 511;
        float mr = (j+1 < WW) ? mask_at(outI, baseO, p+1,  to) : 0.0f;
        float ml = (j-1 >= 0) ? mask_at(outI, baseO, p-1,  to) : 0.0f;
        float mt = (i-1 >= 0) ? mask_at(outI, baseO, p-WW, to) : 0.0f;
        float mb = (i+1 < HH) ? mask_at(outI, baseO, p+WW, to) : 0.0f;
        float dx = (mr - ml) * 0.5f, dy = (mt - mb) * 0.5f;
        float gmo = sqrtf(dx*dx + dy*dy + 1e-6f);
        mr = (j+1 < WW) ? mask_at(tgtI, baseO, p+1,  tt) : 0.0f;
        ml = (j-1 >= 0) ? mask_at(tgtI, baseO, p-1,  tt) : 0.0f;
        mt = (i-1 >= 0) ? mask_at(tgtI, baseO, p-WW, tt) : 0.0f;
        mb = (i+1 < HH) ? mask_at(tgtI, baseO, p+WW, tt) : 0.0f;
        dx = (mr - ml) * 0.5f; dy = (mt - mb) * 0.5f;
        float gmt = sqrtf(dx*dx + dy*dy + 1e-6f);
        sum += fabsf(gmo - gmt);
    }

    __shared__ float sred[256];
    sred[tid] = sum;
    __syncthreads();
    for (int off = 128; off > 0; off >>= 1) {
        if (tid < off) sred[tid] += sred[tid+off];
        __syncthreads();
    }
    if (tid == 0) lgp[blockIdx.x] = sred[0];
}

// ---- K3 combine: reduce all partials in double ---------------------------
__global__ __launch_bounds__(256) void combine_kernel(
    const float* __restrict__ l2p, const float* __restrict__ lgp,
    const float* __restrict__ cesp, const float* __restrict__ xgp,
    float* __restrict__ out) {
    __shared__ double s0[256], s1[256], s2[256];
    const int t = threadIdx.x;
    double a = 0.0, bsum = 0.0, c = 0.0;
    for (int i = t; i < 2048; i += 256) { a += (double)l2p[i]; bsum += (double)lgp[i]; }
    for (int i = t; i < 4096; i += 256) {
        float s = (cesp[4*i] + cesp[4*i+1]) + (cesp[4*i+2] + cesp[4*i+3]);
        c += (double)(__logf(s) - xgp[i]);
    }
    s0[t] = a; s1[t] = bsum; s2[t] = c;
    __syncthreads();
    for (int off = 128; off > 0; off >>= 1) {
        if (t < off) { s0[t] += s0[t+off]; s1[t] += s1[t+off]; s2[t] += s2[t+off]; }
        __syncthreads();
    }
    if (t == 0) {
        double l2 = s0[0] / (double)(3.0 * (double)NPIX);
        double lg = s1[0] / (double)NPIX;
        double ce = s2[0] / (double)ROWS;
        out[0] = (float)(l2 + 1e-4 * lg + 1e-5 * ce);
    }
}

extern "C" void kernel_launch(void* const* d_in, const int* in_sizes, int n_in,
                              void* d_out, int out_size, void* d_ws, size_t ws_size,
                              hipStream_t stream) {
    const float* outI = (const float*)d_in[0];
    const float* tgtI = (const float*)d_in[1];
    const float* X    = (const float*)d_in[2];
    const int*   gt   = (const int*)d_in[3];

    float* l2p  = (float*)d_ws;
    int*   gso  = (int*)((char*)d_ws + 8192);
    int*   gst  = (int*)((char*)d_ws + 16384);
    float* lgp  = (float*)((char*)d_ws + 24576);
    float* cesp = (float*)((char*)d_ws + 32768);
    float* xgp  = (float*)((char*)d_ws + 98304);
    unsigned char* gray = (unsigned char*)d_ws + 131072;
    const size_t need = 131072 + 2 * NPIX;
    const bool useCache = ws_size >= need;

    if (useCache) {
        fused1_kernel<true><<<GRID, 256, 0, stream>>>(
            outI, tgtI, X, gt, l2p, gso, gst, cesp, xgp, gray, gray + NPIX);
        pass2_kernel<<<BB * 16, 256, 0, stream>>>(gray, gray + NPIX, gso, gst, lgp);
    } else {
        fused1_kernel<false><<<GRID, 256, 0, stream>>>(
            outI, tgtI, X, gt, l2p, gso, gst, cesp, xgp, gray, gray);
        pass2_recompute_kernel<<<BB * 16, 256, 0, stream>>>(outI, tgtI, gso, gst, lgp);
    }
    combine_kernel<<<1, 256, 0, stream>>>(l2p, lgp, cesp, xgp, (float*)d_out);
}

// Round 11
// 79.672 us; speedup vs baseline: 1.0338x; 1.0338x over previous
//
#include <hip/hip_runtime.h>
#include <hip/hip_bf16.h>
#include <math.h>

#define BB 128
#define HH 128
#define WW 512
#define HW (HH*WW)            // 65536 pixels per sample
#define NPIX ((size_t)BB*HW)  // 8388608
#define ROWS 4096
#define COLS 10000
#define P1_BLOCKS (BB*16)     // 2048
#define LCE_BLOCKS 2048       // 4 waves/block, 1 wave per half-row (8192 halves)
#define GRID (P1_BLOCKS + LCE_BLOCKS)

// d_ws layout (every slot written every launch; no zeroing needed):
//   [0,8192)        float l2p[2048]    per-block l2 partials
//   [8192,16384)    int gso[2048]      per-block gray sums (out)
//   [16384,24576)   int gst[2048]      per-block gray sums (tgt)
//   [24576,32768)   float lgp[2048]    per-block lg partials
//   [32768,65536)   float cesp[8192]   per-half-row exp sums
//   [65536,81920)   float xgp[4096]    per-row target logit
//   [98304, ...)    u8 gray_out[NPIX], u8 gray_tgt[NPIX]

typedef float vf4 __attribute__((ext_vector_type(4)));

__device__ __forceinline__ int gray_of(float r, float g, float b) {
    int ri = (int)floorf(r * 255.0f);
    int gi = (int)floorf(g * 255.0f);
    int bi = (int)floorf(b * 255.0f);
    return (299 * ri + 587 * gi + 114 * bi) / 1000;
}

__device__ __forceinline__ float e4v(vf4 x) {
    return (__expf(x.x) + __expf(x.y)) + (__expf(x.z) + __expf(x.w));
}

// async global->LDS, 16B per lane; LDS dest = wave-uniform base + lane*16
__device__ __forceinline__ void gload16(const float* g, void* l) {
    __builtin_amdgcn_global_load_lds(
        (const __attribute__((address_space(1))) void*)g,
        (__attribute__((address_space(3))) void*)l, 16, 0, 0);
}

#define WAITV6() do { asm volatile("s_waitcnt vmcnt(6)" ::: "memory"); \
                      __builtin_amdgcn_sched_barrier(0); } while (0)
#define WAITV0() do { asm volatile("s_waitcnt vmcnt(0)" ::: "memory"); \
                      __builtin_amdgcn_sched_barrier(0); } while (0)

// ---- K1: fused pass1 (l2 + gray, LDS-DMA pipeline) and lce (NT loads) ----
template <bool STORE_GRAY>
__global__ __launch_bounds__(256) void fused1_kernel(
    const float* __restrict__ outI, const float* __restrict__ tgtI,
    const float* __restrict__ X, const int* __restrict__ gt,
    float* __restrict__ l2p, int* __restrict__ gso, int* __restrict__ gst,
    float* __restrict__ cesp, float* __restrict__ xgp,
    unsigned char* __restrict__ gout, unsigned char* __restrict__ gtgt) {
    __shared__ __align__(16) unsigned char lds[4][2][6][1024];  // 48 KB, wave-private [w]
    const int tid = threadIdx.x;
    const int bid = blockIdx.x;
    const int w = tid >> 6, lane = tid & 63;

    if ((bid & 1) == 0) {
        // ---------------- pass1: image MSE + gray ----------------
        const int p1    = bid >> 1;          // 0..2047
        const int b     = p1 >> 4;
        const int px0   = (p1 & 15) * 4096;  // block covers 4096 px
        const float* baseO = outI + (size_t)b * 3 * HW + px0 + w * 1024;
        const float* baseT = tgtI + (size_t)b * 3 * HW + px0 + w * 1024;
        uchar4* goB = (uchar4*)(gout + (size_t)b * HW + px0 + w * 1024);
        uchar4* gtB = (uchar4*)(gtgt + (size_t)b * HW + px0 + w * 1024);

        float l2 = 0.0f;
        int so = 0, st = 0;

        auto issue = [&](int c, int p) {
            const float* sO = baseO + c * 256 + lane * 4;
            const float* sT = baseT + c * 256 + lane * 4;
            gload16(sO,          &lds[w][p][0][0]);
            gload16(sO + HW,     &lds[w][p][1][0]);
            gload16(sO + 2*HW,   &lds[w][p][2][0]);
            gload16(sT,          &lds[w][p][3][0]);
            gload16(sT + HW,     &lds[w][p][4][0]);
            gload16(sT + 2*HW,   &lds[w][p][5][0]);
        };
        auto compute = [&](int c, int p) {
            const float4 oR = *(const float4*)&lds[w][p][0][lane*16];
            const float4 oG = *(const float4*)&lds[w][p][1][lane*16];
            const float4 oB = *(const float4*)&lds[w][p][2][lane*16];
            const float4 tR = *(const float4*)&lds[w][p][3][lane*16];
            const float4 tG = *(const float4*)&lds[w][p][4][lane*16];
            const float4 tB = *(const float4*)&lds[w][p][5][lane*16];
            float d;
            d = oR.x-tR.x; l2 += d*d;  d = oR.y-tR.y; l2 += d*d;
            d = oR.z-tR.z; l2 += d*d;  d = oR.w-tR.w; l2 += d*d;
            d = oG.x-tG.x; l2 += d*d;  d = oG.y-tG.y; l2 += d*d;
            d = oG.z-tG.z; l2 += d*d;  d = oG.w-tG.w; l2 += d*d;
            d = oB.x-tB.x; l2 += d*d;  d = oB.y-tB.y; l2 += d*d;
            d = oB.z-tB.z; l2 += d*d;  d = oB.w-tB.w; l2 += d*d;

            int g0 = gray_of(oR.x, oG.x, oB.x);
            int g1 = gray_of(oR.y, oG.y, oB.y);
            int g2 = gray_of(oR.z, oG.z, oB.z);
            int g3 = gray_of(oR.w, oG.w, oB.w);
            so += g0 + g1 + g2 + g3;
            if (STORE_GRAY) goB[c*64 + lane] = make_uchar4((unsigned char)g0,(unsigned char)g1,(unsigned char)g2,(unsigned char)g3);
            g0 = gray_of(tR.x, tG.x, tB.x);
            g1 = gray_of(tR.y, tG.y, tB.y);
            g2 = gray_of(tR.z, tG.z, tB.z);
            g3 = gray_of(tR.w, tG.w, tB.w);
            st += g0 + g1 + g2 + g3;
            if (STORE_GRAY) gtB[c*64 + lane] = make_uchar4((unsigned char)g0,(unsigned char)g1,(unsigned char)g2,(unsigned char)g3);
        };

        issue(0, 0); issue(1, 1);
        WAITV6(); compute(0, 0);
        issue(2, 0);
        WAITV6(); compute(1, 1);
        issue(3, 1);
        WAITV6(); compute(2, 0);
        WAITV0(); compute(3, 1);

        for (int off = 32; off > 0; off >>= 1) {
            l2 += __shfl_down(l2, off);
            so += __shfl_down(so, off);
            st += __shfl_down(st, off);
        }
        __shared__ float wl2[4];
        __shared__ int w1[4], w2[4];
        if (lane == 0) { wl2[w] = l2; w1[w] = so; w2[w] = st; }
        __syncthreads();
        if (tid == 0) {
            l2p[p1] = wl2[0] + wl2[1] + wl2[2] + wl2[3];
            gso[p1] = w1[0] + w1[1] + w1[2] + w1[3];
            gst[p1] = w2[0] + w2[1] + w2[2] + w2[3];
        }
    } else {
        // ------------- lce: one wave per HALF row, nontemporal -------------
        const int unit = (bid >> 1) * 4 + w;       // 0..8191
        const int row  = unit >> 1;
        const int h    = unit & 1;
        const vf4* xh4 = (const vf4*)(X + (size_t)row * COLS + h * 5000);

        float s = 0.0f;
#pragma unroll
        for (int k = 0; k < 18; ++k) {             // float4 idx 0..1151
            vf4 a = __builtin_nontemporal_load(xh4 + lane + k * 64);
            s += e4v(a);
        }
        {   // tail: idx 1152..1249
            vf4 a = __builtin_nontemporal_load(xh4 + 1152 + lane);
            s += e4v(a);
            if (lane < 34) {
                vf4 b2 = __builtin_nontemporal_load(xh4 + 1216 + lane);
                s += e4v(b2);
            }
        }
        for (int off = 32; off > 0; off >>= 1) s += __shfl_down(s, off);
        if (lane == 0) {
            cesp[unit] = s;
            if (h == 0) xgp[row] = X[(size_t)row * COLS + gt[row]];
        }
    }
}

// ---- K2 (cached gray): bit-packed mask gradient --------------------------
__device__ __forceinline__ int mask8(uint2 v, int ti) {
    int m = 0;
#pragma unroll
    for (int k = 0; k < 4; ++k) m |= (((int)((v.x >> (8*k)) & 255) <= ti) ? 1 : 0) << k;
#pragma unroll
    for (int k = 0; k < 4; ++k) m |= (((int)((v.y >> (8*k)) & 255) <= ti) ? 1 : 0) << (k+4);
    return m;
}

__device__ __forceinline__ void grad_bits(const unsigned char* __restrict__ G,
                                          int r, int roff, int ti, int lane,
                                          int& ax, int& vy) {
    uint2 cc = *(const uint2*)(G + roff);
    uint2 aa = *(const uint2*)(G + (r > 0   ? roff - 512 : roff));
    uint2 bb = *(const uint2*)(G + (r < 127 ? roff + 512 : roff));
    int mc = mask8(cc, ti);
    int ma = (r > 0)   ? mask8(aa, ti) : 0;
    int mb = (r < 127) ? mask8(bb, ti) : 0;
    int prev = __shfl_up(mc, 1);
    int next = __shfl_down(mc, 1);
    int lb = ((mc << 1) & 0xFF) | ((lane > 0)  ? ((prev >> 7) & 1) : 0);
    int rb = (mc >> 1)          | ((lane < 63) ? ((next & 1) << 7) : 0);
    ax = lb ^ rb;
    vy = ma ^ mb;
}

__global__ __launch_bounds__(256) void pass2_kernel(
    const unsigned char* __restrict__ gout, const unsigned char* __restrict__ gtgt,
    const int* __restrict__ gso, const int* __restrict__ gst,
    float* __restrict__ lgp) {
    const int tid  = threadIdx.x;
    const int wave = tid >> 6, lane = tid & 63;
    const int b  = blockIdx.x >> 4;   // 16 blocks per sample
    const int rg = blockIdx.x & 15;   // 8 rows per block (4 waves x 2 rows)

    int s_o = 0, s_t = 0;
#pragma unroll
    for (int k = 0; k < 16; ++k) { s_o += gso[b*16 + k]; s_t += gst[b*16 + k]; }
    const int ti_o = s_o >> 16;       // floor(sum/65536): exact threshold
    const int ti_t = s_t >> 16;
    const unsigned char* Go = gout + (size_t)b * HW;
    const unsigned char* Gt = gtgt + (size_t)b * HW;

    const float v0 = sqrtf(1e-6f);
    const float v1 = sqrtf(0.25f + 1e-6f);
    const float v2 = sqrtf(0.5f + 1e-6f);

    float sum = 0.0f;
#pragma unroll
    for (int rr = 0; rr < 2; ++rr) {
        const int r = rg * 8 + wave * 2 + rr;
        const int roff = r * 512 + lane * 8;
        int ax_o, vy_o, ax_t, vy_t;
        grad_bits(Go, r, roff, ti_o, lane, ax_o, vy_o);
        grad_bits(Gt, r, roff, ti_t, lane, ax_t, vy_t);
#pragma unroll
        for (int k = 0; k < 8; ++k) {
            int so = ((ax_o >> k) & 1) + ((vy_o >> k) & 1);
            int st = ((ax_t >> k) & 1) + ((vy_t >> k) & 1);
            float g_o = (so == 0) ? v0 : ((so == 1) ? v1 : v2);
            float g_t = (st == 0) ? v0 : ((st == 1) ? v1 : v2);
            sum += fabsf(g_o - g_t);
        }
    }

    for (int off = 32; off > 0; off >>= 1) sum += __shfl_down(sum, off);
    __shared__ float ws4[4];
    if (lane == 0) ws4[wave] = sum;
    __syncthreads();
    if (tid == 0) lgp[blockIdx.x] = ws4[0] + ws4[1] + ws4[2] + ws4[3];
}

// ---- K2 fallback (no gray cache): recompute gray from images -------------
__device__ __forceinline__ float mask_at(const float* __restrict__ img, size_t base, int p, float thres) {
    float r = img[base + p], g = img[base + p + HW], b = img[base + p + 2*HW];
    return ((float)gray_of(r, g, b) > thres) ? 0.0f : 1.0f;
}

__global__ __launch_bounds__(256) void pass2_recompute_kernel(
    const float* __restrict__ outI, const float* __restrict__ tgtI,
    const int* __restrict__ gso, const int* __restrict__ gst,
    float* __restrict__ lgp) {
    const int tid   = threadIdx.x;
    const int b     = blockIdx.x >> 4;
    const int chunk = blockIdx.x & 15;
    int s_o = 0, s_t = 0;
    for (int k = 0; k < 16; ++k) { s_o += gso[b*16 + k]; s_t += gst[b*16 + k]; }
    const float to = (float)s_o * (1.0f/65536.0f);
    const float tt = (float)s_t * (1.0f/65536.0f);
    const size_t baseO = (size_t)b * 3 * HW;

    float sum = 0.0f;
    for (int u = 0; u < 16; ++u) {
        int p = chunk * 4096 + u * 256 + tid;
        int i = p >> 9, j = p & 511;
        float mr = (j+1 < WW) ? mask_at(outI, baseO, p+1,  to) : 0.0f;
        float ml = (j-1 >= 0) ? mask_at(outI, baseO, p-1,  to) : 0.0f;
        float mt = (i-1 >= 0) ? mask_at(outI, baseO, p-WW, to) : 0.0f;
        float mb = (i+1 < HH) ? mask_at(outI, baseO, p+WW, to) : 0.0f;
        float dx = (mr - ml) * 0.5f, dy = (mt - mb) * 0.5f;
        float gmo = sqrtf(dx*dx + dy*dy + 1e-6f);
        mr = (j+1 < WW) ? mask_at(tgtI, baseO, p+1,  tt) : 0.0f;
        ml = (j-1 >= 0) ? mask_at(tgtI, baseO, p-1,  tt) : 0.0f;
        mt = (i-1 >= 0) ? mask_at(tgtI, baseO, p-WW, tt) : 0.0f;
        mb = (i+1 < HH) ? mask_at(tgtI, baseO, p+WW, tt) : 0.0f;
        dx = (mr - ml) * 0.5f; dy = (mt - mb) * 0.5f;
        float gmt = sqrtf(dx*dx + dy*dy + 1e-6f);
        sum += fabsf(gmo - gmt);
    }

    __shared__ float sred[256];
    sred[tid] = sum;
    __syncthreads();
    for (int off = 128; off > 0; off >>= 1) {
        if (tid < off) sred[tid] += sred[tid+off];
        __syncthreads();
    }
    if (tid == 0) lgp[blockIdx.x] = sred[0];
}

// ---- K3 combine: reduce all partials in double ---------------------------
__global__ __launch_bounds__(256) void combine_kernel(
    const float* __restrict__ l2p, const float* __restrict__ lgp,
    const float* __restrict__ cesp, const float* __restrict__ xgp,
    float* __restrict__ out) {
    __shared__ double s0[256], s1[256], s2[256];
    const int t = threadIdx.x;
    double a = 0.0, bsum = 0.0, c = 0.0;
    for (int i = t; i < 2048; i += 256) { a += (double)l2p[i]; bsum += (double)lgp[i]; }
    for (int i = t; i < 4096; i += 256)
        c += (double)(__logf(cesp[2*i] + cesp[2*i+1]) - xgp[i]);
    s0[t] = a; s1[t] = bsum; s2[t] = c;
    __syncthreads();
    for (int off = 128; off > 0; off >>= 1) {
        if (t < off) { s0[t] += s0[t+off]; s1[t] += s1[t+off]; s2[t] += s2[t+off]; }
        __syncthreads();
    }
    if (t == 0) {
        double l2 = s0[0] / (double)(3.0 * (double)NPIX);
        double lg = s1[0] / (double)NPIX;
        double ce = s2[0] / (double)ROWS;
        out[0] = (float)(l2 + 1e-4 * lg + 1e-5 * ce);
    }
}

extern "C" void kernel_launch(void* const* d_in, const int* in_sizes, int n_in,
                              void* d_out, int out_size, void* d_ws, size_t ws_size,
                              hipStream_t stream) {
    const float* outI = (const float*)d_in[0];
    const float* tgtI = (const float*)d_in[1];
    const float* X    = (const float*)d_in[2];
    const int*   gt   = (const int*)d_in[3];

    float* l2p  = (float*)d_ws;
    int*   gso  = (int*)((char*)d_ws + 8192);
    int*   gst  = (int*)((char*)d_ws + 16384);
    float* lgp  = (float*)((char*)d_ws + 24576);
    float* cesp = (float*)((char*)d_ws + 32768);
    float* xgp  = (float*)((char*)d_ws + 65536);
    unsigned char* gray = (unsigned char*)d_ws + 98304;
    const size_t need = 98304 + 2 * NPIX;
    const bool useCache = ws_size >= need;

    if (useCache) {
        fused1_kernel<true><<<GRID, 256, 0, stream>>>(
            outI, tgtI, X, gt, l2p, gso, gst, cesp, xgp, gray, gray + NPIX);
        pass2_kernel<<<BB * 16, 256, 0, stream>>>(gray, gray + NPIX, gso, gst, lgp);
    } else {
        fused1_kernel<false><<<GRID, 256, 0, stream>>>(
            outI, tgtI, X, gt, l2p, gso, gst, cesp, xgp, gray, gray);
        pass2_recompute_kernel<<<BB * 16, 256, 0, stream>>>(outI, tgtI, gso, gst, lgp);
    }
    combine_kernel<<<1, 256, 0, stream>>>(l2p, lgp, cesp, xgp, (float*)d_out);
}